// Round 2
// baseline (161.229 us; speedup 1.0000x reference)
//
#include <hip/hip_runtime.h>
#include <hip/hip_cooperative_groups.h>
#include <math.h>

namespace cg = cooperative_groups;

#define BB 8
#define NN 512
#define MM 512
#define HID 64

// ws layout (floats)
#define WS_BLKMAX   0                     // 256 per-block maxima (every slot written each call)
#define WS_CNT      256                   // 8 uint (atomicAdd; zeroed)
#define WS_WM       264                   // B*M (zeroed)
#define WS_P1       (WS_WM + BB*MM)       // B*M*3 (zeroed)
#define WS_ZERO_N   (8 + BB*MM + BB*MM*3) // 16392 words starting at WS_CNT

__device__ __forceinline__ float wredSum(float v){
  #pragma unroll
  for (int off=32; off; off>>=1) v += __shfl_xor(v, off);
  return v;
}
__device__ __forceinline__ int wredSumI(int v){
  #pragma unroll
  for (int off=32; off; off>>=1) v += __shfl_xor(v, off);
  return v;
}
__device__ __forceinline__ float wredMax(float v){
  #pragma unroll
  for (int off=32; off; off>>=1) v = fmaxf(v, __shfl_xor(v, off));
  return v;
}

// count of sorted stb[0..63] entries < s  (segment index, 0..64)
__device__ __forceinline__ int seg_lookup(const float* stb, float s){
  int k = (stb[31] < s) ? 32 : 0;
  k += (stb[k+15] < s) ? 16 : 0;
  k += (stb[k+7]  < s) ? 8  : 0;
  k += (stb[k+3]  < s) ? 4  : 0;
  k += (stb[k+1]  < s) ? 2  : 0;
  k += (stb[k]    < s) ? 1  : 0;
  if (k == 63 && stb[63] < s) k = 64;
  return k;
}

__global__ __launch_bounds__(256, 1) void k_fused(
    const float* __restrict__ sc, const float* __restrict__ pos1,
    const float* __restrict__ pos2,
    const float* __restrict__ w1, const float* __restrict__ b1,
    const float* __restrict__ w2, const float* __restrict__ b2,
    float* __restrict__ ws, float* __restrict__ out)
{
  __shared__ float ssc[16*512];                       // 32 KB score tile
  __shared__ float traw[64];
  __shared__ float stb[64], sApos[64], sAneg[64], sBpos[64], sBneg[64];
  __shared__ float sAseg[65], sBseg[65];
  __shared__ float sp1[48];
  __shared__ float sred[4];
  __shared__ float sconst;

  cg::grid_group grid = cg::this_grid();
  const int bid = blockIdx.x, t = threadIdx.x;
  const int b = bid >> 5, tile = bid & 31, n0 = tile*16;
  float* blkmax = ws + WS_BLKMAX;
  unsigned* cnt = (unsigned*)(ws + WS_CNT);
  float* Wm = ws + WS_WM;
  float* P1 = ws + WS_P1;

  // ---------------- phase A: zero ws, stage scores, build PL table ----------------
  { int g = bid*256 + t; if (g < WS_ZERO_N) ws[WS_CNT + g] = 0.f; }

  const float4* src = (const float4*)(sc + ((size_t)(b*NN + n0))*MM);
  float4* dst = (float4*)ssc;
  float mx = 0.f;
  #pragma unroll
  for (int i=0;i<8;++i){
    float4 v = src[t + i*256];
    mx = fmaxf(mx, fmaxf(fmaxf(v.x,v.y), fmaxf(v.z,v.w)));
    dst[t + i*256] = v;
  }
  if (t < 48) sp1[t] = pos1[((size_t)(b*NN + n0))*3 + t];

  float tp = 0.f, aC = 0.f, bC = 0.f, cC = 0.f; int cls = 2;
  if (t < HID){
    float wv1 = w1[t], bv1 = b1[t], wv2 = w2[t];
    aC = wv2*wv1; bC = wv2*bv1;
    if (wv1 > 0.f){ cls = 0; tp = -bv1/wv1; }
    else if (wv1 < 0.f){ cls = 1; tp = -bv1/wv1; }
    else { cls = 2; tp = -1e30f; cC = wv2*fmaxf(bv1, 0.f); }
    traw[t] = tp;
  }
  __syncthreads();
  if (t < HID){                                  // threads 0..63 == wave 0
    int r = 0;
    #pragma unroll
    for (int j=0;j<HID;++j){
      float tj = traw[j];
      r += (tj < tp || (tj == tp && j < t)) ? 1 : 0;
    }
    stb[r]   = tp;
    sApos[r] = (cls==0) ? aC : 0.f;
    sAneg[r] = (cls==1) ? aC : 0.f;
    sBpos[r] = (cls==0) ? bC : 0.f;
    sBneg[r] = (cls==1) ? bC : 0.f;
    float cCs = wredSum(cC);
    if (t == 0) sconst = cCs + b2[0];
  }
  mx = wredMax(mx);
  if ((t & 63) == 0) sred[t >> 6] = mx;
  __syncthreads();
  if (t == 0){
    blkmax[bid] = fmaxf(fmaxf(sred[0],sred[1]), fmaxf(sred[2],sred[3]));
    float totNA = 0.f, totNB = 0.f;
    for (int k=0;k<64;++k){ totNA += sAneg[k]; totNB += sBneg[k]; }
    float Apos = 0.f, Bpos = 0.f, Aneg = totNA, Bneg = totNB, cB = sconst;
    for (int k=0;k<=64;++k){
      sAseg[k] = Apos + Aneg;
      sBseg[k] = Bpos + Bneg + cB;
      if (k < 64){ Apos += sApos[k]; Aneg -= sAneg[k]; Bpos += sBpos[k]; Bneg -= sBneg[k]; }
    }
  }
  grid.sync();

  // ---------------- phase B: weights + sufficient statistics ----------------
  float bm = 0.f;
  #pragma unroll
  for (int j=0;j<32;++j) bm = fmaxf(bm, blkmax[b*32 + j]);
  const float thr = 0.1f * bm;

  const int c0 = 2*t;
  float wm0=0.f, wm1=0.f;
  float pa0x=0.f,pa0y=0.f,pa0z=0.f, pa1x=0.f,pa1y=0.f,pa1z=0.f;
  int cl = 0;
  #pragma unroll
  for (int r=0;r<16;++r){
    float2 sv = *(const float2*)&ssc[r*512 + c0];
    float s0 = sv.x, s1 = sv.y;
    int k0 = seg_lookup(stb, s0);
    int k1 = seg_lookup(stb, s1);
    float g0 = fmaf(sAseg[k0], s0, sBseg[k0]);
    float g1 = fmaf(sAseg[k1], s1, sBseg[k1]);
    float v0 = 1.f/(1.f + __expf(-g0));
    float v1 = 1.f/(1.f + __expf(-g1));
    bool m0 = s0 > thr, m1 = s1 > thr;
    float w0 = m0 ? v0 : 0.f;
    float w1_ = m1 ? v1 : 0.f;
    cl += (int)m0 + (int)m1;
    wm0 += w0; wm1 += w1_;
    float px = sp1[r*3+0], py = sp1[r*3+1], pz = sp1[r*3+2];
    pa0x = fmaf(w0, px, pa0x); pa0y = fmaf(w0, py, pa0y); pa0z = fmaf(w0, pz, pa0z);
    pa1x = fmaf(w1_,px, pa1x); pa1y = fmaf(w1_,py, pa1y); pa1z = fmaf(w1_,pz, pa1z);
  }
  {
    int mi = b*MM + c0;
    atomicAdd(Wm + mi,     wm0);
    atomicAdd(Wm + mi + 1, wm1);
    atomicAdd(P1 + (size_t)mi*3 + 0, pa0x);
    atomicAdd(P1 + (size_t)mi*3 + 1, pa0y);
    atomicAdd(P1 + (size_t)mi*3 + 2, pa0z);
    atomicAdd(P1 + (size_t)(mi+1)*3 + 0, pa1x);
    atomicAdd(P1 + (size_t)(mi+1)*3 + 1, pa1y);
    atomicAdd(P1 + (size_t)(mi+1)*3 + 2, pa1z);
    cl = wredSumI(cl);
    if ((t & 63) == 0) atomicAdd(cnt + b, (unsigned)cl);
  }
  grid.sync();

  // ---------------- phase C: centroids, H, Horn-quaternion Kabsch ----------------
  if (bid < BB){
    const int fb = bid;
    auto bred = [&](float v)->float{
      v = wredSum(v);
      __syncthreads();
      if ((t & 63) == 0) sred[t >> 6] = v;
      __syncthreads();
      return sred[0]+sred[1]+sred[2]+sred[3];
    };
    const int m0i = t, m1i = t + 256;
    float wmA = Wm[fb*MM + m0i], wmB = Wm[fb*MM + m1i];
    const float* pA = P1 + (size_t)(fb*MM + m0i)*3;
    const float* pB = P1 + (size_t)(fb*MM + m1i)*3;
    float p1Ax=pA[0], p1Ay=pA[1], p1Az=pA[2];
    float p1Bx=pB[0], p1By=pB[1], p1Bz=pB[2];
    const float* qA = pos2 + (size_t)(fb*MM + m0i)*3;
    const float* qB = pos2 + (size_t)(fb*MM + m1i)*3;
    float p2Ax=qA[0], p2Ay=qA[1], p2Az=qA[2];
    float p2Bx=qB[0], p2By=qB[1], p2Bz=qB[2];

    float S = bred(wmA + wmB) + 1e-8f;
    float inv = 1.f/S;
    float c1x = bred(p1Ax+p1Bx)*inv, c1y = bred(p1Ay+p1By)*inv, c1z = bred(p1Az+p1Bz)*inv;
    float c2x = bred(fmaf(wmA,p2Ax, wmB*p2Bx))*inv;
    float c2y = bred(fmaf(wmA,p2Ay, wmB*p2By))*inv;
    float c2z = bred(fmaf(wmA,p2Az, wmB*p2Bz))*inv;

    float aAx = p1Ax*inv - wmA*inv*c1x, aAy = p1Ay*inv - wmA*inv*c1y, aAz = p1Az*inv - wmA*inv*c1z;
    float aBx = p1Bx*inv - wmB*inv*c1x, aBy = p1By*inv - wmB*inv*c1y, aBz = p1Bz*inv - wmB*inv*c1z;
    float qAx = p2Ax - c2x, qAy = p2Ay - c2y, qAz = p2Az - c2z;
    float qBx = p2Bx - c2x, qBy = p2By - c2y, qBz = p2Bz - c2z;

    float H[9];
    H[0] = bred(aAx*qAx + aBx*qBx); H[1] = bred(aAx*qAy + aBx*qBy); H[2] = bred(aAx*qAz + aBx*qBz);
    H[3] = bred(aAy*qAx + aBy*qBx); H[4] = bred(aAy*qAy + aBy*qBy); H[5] = bred(aAy*qAz + aBy*qBz);
    H[6] = bred(aAz*qAx + aBz*qBx); H[7] = bred(aAz*qAy + aBz*qBy); H[8] = bred(aAz*qAz + aBz*qBz);

    if (t == 0){
      float Sxx=H[0],Sxy=H[1],Sxz=H[2];
      float Syx=H[3],Syy=H[4],Syz=H[5];
      float Szx=H[6],Szy=H[7],Szz=H[8];
      float Kq[4][4];
      Kq[0][0]=Sxx+Syy+Szz; Kq[0][1]=Syz-Szy;     Kq[0][2]=Szx-Sxz;     Kq[0][3]=Sxy-Syx;
      Kq[1][0]=Kq[0][1];    Kq[1][1]=Sxx-Syy-Szz; Kq[1][2]=Sxy+Syx;     Kq[1][3]=Szx+Sxz;
      Kq[2][0]=Kq[0][2];    Kq[2][1]=Kq[1][2];    Kq[2][2]=Syy-Sxx-Szz; Kq[2][3]=Syz+Szy;
      Kq[3][0]=Kq[0][3];    Kq[3][1]=Kq[1][3];    Kq[3][2]=Kq[2][3];    Kq[3][3]=Szz-Sxx-Syy;
      float fn=0.f;
      #pragma unroll
      for (int i=0;i<4;++i){
        #pragma unroll
        for (int j=0;j<4;++j) fn += Kq[i][j]*Kq[i][j];
      }
      float sig = sqrtf(fn) + 1e-30f;
      #pragma unroll
      for (int i=0;i<4;++i) Kq[i][i] += sig;
      fn=0.f;
      #pragma unroll
      for (int i=0;i<4;++i){
        #pragma unroll
        for (int j=0;j<4;++j) fn += Kq[i][j]*Kq[i][j];
      }
      float nsc = rsqrtf(fn + 1e-38f);
      #pragma unroll
      for (int i=0;i<4;++i){
        #pragma unroll
        for (int j=0;j<4;++j) Kq[i][j] *= nsc;
      }
      #pragma unroll
      for (int sqi=0; sqi<4; ++sqi){
        float Bq[4][4]; float f2=0.f;
        #pragma unroll
        for (int i=0;i<4;++i){
          #pragma unroll
          for (int j=0;j<4;++j){
            float v=0.f;
            #pragma unroll
            for (int k=0;k<4;++k) v = fmaf(Kq[i][k],Kq[k][j],v);
            Bq[i][j]=v; f2 += v*v;
          }
        }
        float isc = rsqrtf(f2 + 1e-38f);
        #pragma unroll
        for (int i=0;i<4;++i){
          #pragma unroll
          for (int j=0;j<4;++j) Kq[i][j] = Bq[i][j]*isc;
        }
      }
      float q0=1.f, q1=0.31f, q2=0.67f, q3=0.93f;
      #pragma unroll
      for (int it=0; it<16; ++it){
        float n0 = Kq[0][0]*q0+Kq[0][1]*q1+Kq[0][2]*q2+Kq[0][3]*q3;
        float n1 = Kq[1][0]*q0+Kq[1][1]*q1+Kq[1][2]*q2+Kq[1][3]*q3;
        float n2 = Kq[2][0]*q0+Kq[2][1]*q1+Kq[2][2]*q2+Kq[2][3]*q3;
        float n3 = Kq[3][0]*q0+Kq[3][1]*q1+Kq[3][2]*q2+Kq[3][3]*q3;
        float nn = rsqrtf(n0*n0+n1*n1+n2*n2+n3*n3 + 1e-38f);
        q0=n0*nn; q1=n1*nn; q2=n2*nn; q3=n3*nn;
      }
      float R00=q0*q0+q1*q1-q2*q2-q3*q3, R01=2.f*(q1*q2-q0*q3),       R02=2.f*(q1*q3+q0*q2);
      float R10=2.f*(q1*q2+q0*q3),       R11=q0*q0-q1*q1+q2*q2-q3*q3, R12=2.f*(q2*q3-q0*q1);
      float R20=2.f*(q1*q3-q0*q2),       R21=2.f*(q2*q3+q0*q1),       R22=q0*q0-q1*q1-q2*q2+q3*q3;
      float tx = c2x - (R00*c1x + R01*c1y + R02*c1z);
      float ty = c2y - (R10*c1x + R11*c1y + R12*c1z);
      float tz = c2z - (R20*c1x + R21*c1y + R22*c1z);
      float tn = sqrtf(tx*tx+ty*ty+tz*tz);
      float itn = 1.f/fmaxf(tn, 1e-12f);
      tx*=itn; ty*=itn; tz*=itn;
      if (cnt[fb] < 5u){
        R00=1.f;R01=0.f;R02=0.f; R10=0.f;R11=1.f;R12=0.f; R20=0.f;R21=0.f;R22=1.f;
        tx=0.f; ty=0.f; tz=1.f;
      }
      float* Ro = out + fb*9;
      Ro[0]=R00;Ro[1]=R01;Ro[2]=R02;Ro[3]=R10;Ro[4]=R11;Ro[5]=R12;Ro[6]=R20;Ro[7]=R21;Ro[8]=R22;
      float* to = out + BB*9 + fb*3;
      to[0]=tx; to[1]=ty; to[2]=tz;
    }
  }
}

extern "C" void kernel_launch(void* const* d_in, const int* in_sizes, int n_in,
                              void* d_out, int out_size, void* d_ws, size_t ws_size,
                              hipStream_t stream){
  const float* pos1 = (const float*)d_in[0];
  const float* pos2 = (const float*)d_in[1];
  const float* sc   = (const float*)d_in[2];
  // d_in[3] = K (unused by the reference)
  const float* w1   = (const float*)d_in[4];
  const float* b1   = (const float*)d_in[5];
  const float* w2   = (const float*)d_in[6];
  const float* b2   = (const float*)d_in[7];
  float* ws  = (float*)d_ws;
  float* out = (float*)d_out;

  void* args[] = { (void*)&sc, (void*)&pos1, (void*)&pos2,
                   (void*)&w1, (void*)&b1, (void*)&w2, (void*)&b2,
                   (void*)&ws, (void*)&out };
  hipLaunchCooperativeKernel((const void*)k_fused, dim3(BB*32), dim3(256), args, 0, stream);
}

// Round 3
// 93.193 us; speedup vs baseline: 1.7301x; 1.7301x over previous
//
#include <hip/hip_runtime.h>
#include <math.h>

#define BB 8
#define NN 512
#define MM 512
#define HID 64
#define TBL_N 2048

// ws layout (floats) — every slot written before read; NO init required.
#define WS_BLKMAX 0                       // 256: per-(batch,chunk) maxima (k_prep blocks 1..256)
#define WS_TBL    256                     // 2*TBL_N: (A,B) chord table (k_prep block 0)
#define WS_CNTP   (WS_TBL + 2*TBL_N)      // 512: per-block mask counts (k_stats)
#define WS_PART   (WS_CNTP + 512)         // 512 blocks * 16 cols * 4 stats (k_stats)

__device__ __forceinline__ float wredSum(float v){
  #pragma unroll
  for (int off=32; off; off>>=1) v += __shfl_xor(v, off);
  return v;
}
__device__ __forceinline__ float wredMax(float v){
  #pragma unroll
  for (int off=32; off; off>>=1) v = fmaxf(v, __shfl_xor(v, off));
  return v;
}
// count of sorted stb[0..63] entries < s
__device__ __forceinline__ int seg_lookup(const float* stb, float s){
  int k = (stb[31] < s) ? 32 : 0;
  k += (stb[k+15] < s) ? 16 : 0;
  k += (stb[k+7]  < s) ? 8  : 0;
  k += (stb[k+3]  < s) ? 4  : 0;
  k += (stb[k+1]  < s) ? 2  : 0;
  k += (stb[k]    < s) ? 1  : 0;
  if (k == 63 && stb[63] < s) k = 64;
  return k;
}

// ---------- k1: block 0 builds chord table; blocks 1..256 compute per-chunk maxima ----------
__global__ __launch_bounds__(256) void k_prep(const float* __restrict__ sc,
    const float* __restrict__ w1, const float* __restrict__ b1,
    const float* __restrict__ w2, const float* __restrict__ b2,
    float* __restrict__ ws)
{
  __shared__ float sred[4];
  __shared__ float traw[64], stb[64], sApos[64], sAneg[64], sBpos[64], sBneg[64];
  __shared__ float sAseg[65], sBseg[65];
  __shared__ float Gt[TBL_N+1];
  __shared__ float sconst;
  const int t = threadIdx.x;

  if (blockIdx.x == 0){
    // exact piecewise-linear decomposition of g(s) = sum w2_i*relu(w1_i*s+b1_i) + b2
    float tp=0.f, aC=0.f, bC=0.f, cC=0.f; int cls=2;
    if (t < HID){
      float wv1=w1[t], bv1=b1[t], wv2=w2[t];
      aC = wv2*wv1; bC = wv2*bv1;
      if (wv1 > 0.f){ cls=0; tp=-bv1/wv1; }
      else if (wv1 < 0.f){ cls=1; tp=-bv1/wv1; }
      else { cls=2; tp=-1e30f; cC = wv2*fmaxf(bv1,0.f); }
      traw[t]=tp;
    }
    __syncthreads();
    if (t < HID){                                // wave 0
      int r=0;
      for (int j=0;j<HID;++j){
        float tj=traw[j];
        r += (tj<tp || (tj==tp && j<t)) ? 1 : 0;
      }
      stb[r]=tp;
      sApos[r]=(cls==0)?aC:0.f; sAneg[r]=(cls==1)?aC:0.f;
      sBpos[r]=(cls==0)?bC:0.f; sBneg[r]=(cls==1)?bC:0.f;
      float cCs = wredSum(cC);
      if (t==0) sconst = cCs + b2[0];
    }
    __syncthreads();
    if (t==0){
      float totNA=0.f, totNB=0.f;
      for (int k=0;k<HID;++k){ totNA+=sAneg[k]; totNB+=sBneg[k]; }
      float Apos=0.f, Bpos=0.f, Aneg=totNA, Bneg=totNB;
      for (int k=0;k<=HID;++k){
        sAseg[k]=Apos+Aneg; sBseg[k]=Bpos+Bneg+sconst;
        if (k<HID){ Apos+=sApos[k]; Aneg-=sAneg[k]; Bpos+=sBpos[k]; Bneg-=sBneg[k]; }
      }
    }
    __syncthreads();
    {   // sample g at 2049 grid points (one search + pointer advance)
      const float hstep = 1.f/(float)TBL_N;
      int j0 = t*8;
      int k = seg_lookup(stb, (float)j0*hstep);
      #pragma unroll
      for (int u=0;u<8;++u){
        int j=j0+u; float x=(float)j*hstep;
        while (k<HID && stb[k]<x) ++k;
        Gt[j]=fmaf(sAseg[k],x,sBseg[k]);
      }
      if (t==255){
        float x=1.f;
        while (k<HID && stb[k]<x) ++k;
        Gt[TBL_N]=fmaf(sAseg[k],x,sBseg[k]);
      }
    }
    __syncthreads();
    {   // chord (A,B) per cell
      float2* tbl=(float2*)(ws+WS_TBL);
      const float hstep=1.f/(float)TBL_N;
      #pragma unroll
      for (int u=0;u<8;++u){
        int j=t*8+u;
        float A=(Gt[j+1]-Gt[j])*(float)TBL_N;
        float Bc=Gt[j]-A*((float)j*hstep);
        tbl[j]=make_float2(A,Bc);
      }
    }
  } else {
    const int bid=blockIdx.x-1, b=bid>>5, chunk=bid&31;
    const float4* p=(const float4*)(sc+(size_t)b*NN*MM)+(size_t)chunk*2048+t;
    float m=0.f;   // scores uniform[0,1): nonnegative
    #pragma unroll
    for (int i=0;i<8;++i){
      float4 v=p[i*256];
      m=fmaxf(m, fmaxf(fmaxf(v.x,v.y), fmaxf(v.z,v.w)));
    }
    m=wredMax(m);
    if ((t&63)==0) sred[t>>6]=m;
    __syncthreads();
    if (t==0) ws[WS_BLKMAX+bid]=fmaxf(fmaxf(sred[0],sred[1]),fmaxf(sred[2],sred[3]));
  }
}

// ---------- k2: column-tile stats, block-private (NO atomics) ----------
// 512 blocks = 8 batches x 32 col-tiles(16 cols) x 2 row-halves(256 rows).
// thread t: colpair cp=t&7 (cols m0+2cp, +1), rowlane rl=t>>3; rows rl+32k, k<8.
__global__ __launch_bounds__(256) void k_stats(const float* __restrict__ sc,
    const float* __restrict__ pos1, float* __restrict__ ws)
{
  __shared__ float2 stab[TBL_N];       // 16 KB
  __shared__ float sp1[768];           // 3 KB: this half's 256 rows x 3
  __shared__ float wredm[4][8][9];
  __shared__ float sthr;
  const int t=threadIdx.x, bid=blockIdx.x;
  const int b=bid>>6, r=bid&63, mt=r>>1, half=r&1;
  const int m0=mt*16, n0=half*256;

  { const float4* src=(const float4*)(ws+WS_TBL);
    float4* dst=(float4*)stab;
    dst[t]=src[t]; dst[t+256]=src[t+256]; dst[t+512]=src[t+512]; dst[t+768]=src[t+768]; }
  { const float* src=pos1+((size_t)(b*NN+n0))*3;
    sp1[t]=src[t]; sp1[t+256]=src[t+256]; sp1[t+512]=src[t+512]; }
  if (t<64){
    float v=(t<32)? ws[WS_BLKMAX+b*32+t] : 0.f;
    v=wredMax(v);
    if (t==0) sthr=0.1f*v;
  }
  __syncthreads();

  const float thr=sthr;
  const int cp=t&7, rl=t>>3;
  const float2* srow=(const float2*)(sc+((size_t)(b*NN+n0))*MM+m0);
  float a0=0.f,x0=0.f,y0=0.f,z0=0.f, a1=0.f,x1=0.f,y1=0.f,z1=0.f;
  int cnt=0;
  #pragma unroll
  for (int k=0;k<8;++k){
    const int nl=rl+32*k;
    float2 s=srow[nl*256+cp];
    int i0=min((int)(s.x*(float)TBL_N),TBL_N-1);
    int i1=min((int)(s.y*(float)TBL_N),TBL_N-1);
    float2 ab0=stab[i0], ab1=stab[i1];
    float g0=fmaf(ab0.x,s.x,ab0.y);
    float g1=fmaf(ab1.x,s.y,ab1.y);
    float v0=1.f/(1.f+__expf(-g0));
    float v1=1.f/(1.f+__expf(-g1));
    bool msk0=s.x>thr, msk1=s.y>thr;
    float w0=msk0?v0:0.f, w1v=msk1?v1:0.f;
    cnt += (int)msk0 + (int)msk1;
    float px=sp1[nl*3], py=sp1[nl*3+1], pz=sp1[nl*3+2];
    a0+=w0;  x0=fmaf(w0,px,x0);  y0=fmaf(w0,py,y0);  z0=fmaf(w0,pz,z0);
    a1+=w1v; x1=fmaf(w1v,px,x1); y1=fmaf(w1v,py,y1); z1=fmaf(w1v,pz,z1);
  }
  float vals[9]={a0,x0,y0,z0,a1,x1,y1,z1,(float)cnt};
  #pragma unroll
  for (int j=0;j<9;++j){          // reduce over rl within wave (lanes stride 8)
    float v=vals[j];
    v+=__shfl_xor(v,8); v+=__shfl_xor(v,16); v+=__shfl_xor(v,32);
    vals[j]=v;
  }
  const int lane=t&63, wv=t>>6;
  if (lane<8){
    #pragma unroll
    for (int j=0;j<9;++j) wredm[wv][lane][j]=vals[j];
  }
  __syncthreads();
  if (t<64){                       // t = c*4 + stat
    const int c=t>>2, st=t&3, cpp=c>>1, odd=c&1;
    float sum=wredm[0][cpp][odd*4+st]+wredm[1][cpp][odd*4+st]
             +wredm[2][cpp][odd*4+st]+wredm[3][cpp][odd*4+st];
    ws[WS_PART + bid*64 + t]=sum;
  } else if (t==64){
    float csum=0.f;
    #pragma unroll
    for (int w=0;w<4;++w)
      #pragma unroll
      for (int c8=0;c8<8;++c8) csum+=wredm[w][c8][8];
    ws[WS_CNTP+bid]=csum;
  }
}

template<int K>
__device__ __forceinline__ void bredN(float* v, float* sredN, int t){
  #pragma unroll
  for (int j=0;j<K;++j) v[j]=wredSum(v[j]);
  __syncthreads();
  if ((t&63)==0){
    #pragma unroll
    for (int j=0;j<K;++j) sredN[(t>>6)*K+j]=v[j];
  }
  __syncthreads();
  #pragma unroll
  for (int j=0;j<K;++j) v[j]=sredN[j]+sredN[K+j]+sredN[2*K+j]+sredN[3*K+j];
}

// ---------- k3: assemble stats, centroids, H, Horn-quaternion Kabsch ----------
__global__ __launch_bounds__(256) void k_final(const float* __restrict__ pos2,
    const float* __restrict__ ws, float* __restrict__ out)
{
  __shared__ float sredN[4*9];
  const int b=blockIdx.x, t=threadIdx.x;

  float wm[2], p1s[2][3], p2v[2][3];
  #pragma unroll
  for (int h2=0; h2<2; ++h2){
    const int m=t+h2*256, mt=m>>4, c=m&15;
    const float* pa=ws+WS_PART+((size_t)((b*32+mt)*2))*64 + c*4;
    const float* pb=pa+64;
    wm[h2]=pa[0]+pb[0];
    p1s[h2][0]=pa[1]+pb[1]; p1s[h2][1]=pa[2]+pb[2]; p1s[h2][2]=pa[3]+pb[3];
    const float* q=pos2+((size_t)(b*MM+m))*3;
    p2v[h2][0]=q[0]; p2v[h2][1]=q[1]; p2v[h2][2]=q[2];
  }
  float cf=(t<64)? ws[WS_CNTP+b*64+t] : 0.f;

  float v8[8];
  v8[0]=wm[0]+wm[1];
  v8[1]=cf;
  v8[2]=p1s[0][0]+p1s[1][0]; v8[3]=p1s[0][1]+p1s[1][1]; v8[4]=p1s[0][2]+p1s[1][2];
  v8[5]=fmaf(wm[0],p2v[0][0],wm[1]*p2v[1][0]);
  v8[6]=fmaf(wm[0],p2v[0][1],wm[1]*p2v[1][1]);
  v8[7]=fmaf(wm[0],p2v[0][2],wm[1]*p2v[1][2]);
  bredN<8>(v8, sredN, t);

  const float S=v8[0]+1e-8f, inv=1.f/S;
  const float cntTot=v8[1];
  const float c1x=v8[2]*inv, c1y=v8[3]*inv, c1z=v8[4]*inv;
  const float c2x=v8[5]*inv, c2y=v8[6]*inv, c2z=v8[7]*inv;

  float Hv[9]={0,0,0,0,0,0,0,0,0};
  #pragma unroll
  for (int h2=0; h2<2; ++h2){
    float wn=wm[h2]*inv;
    float ax=p1s[h2][0]*inv - wn*c1x;
    float ay=p1s[h2][1]*inv - wn*c1y;
    float az=p1s[h2][2]*inv - wn*c1z;
    float qx=p2v[h2][0]-c2x, qy=p2v[h2][1]-c2y, qz=p2v[h2][2]-c2z;
    Hv[0]=fmaf(ax,qx,Hv[0]); Hv[1]=fmaf(ax,qy,Hv[1]); Hv[2]=fmaf(ax,qz,Hv[2]);
    Hv[3]=fmaf(ay,qx,Hv[3]); Hv[4]=fmaf(ay,qy,Hv[4]); Hv[5]=fmaf(ay,qz,Hv[5]);
    Hv[6]=fmaf(az,qx,Hv[6]); Hv[7]=fmaf(az,qy,Hv[7]); Hv[8]=fmaf(az,qz,Hv[8]);
  }
  bredN<9>(Hv, sredN, t);

  if (t==0){
    float Sxx=Hv[0],Sxy=Hv[1],Sxz=Hv[2];
    float Syx=Hv[3],Syy=Hv[4],Syz=Hv[5];
    float Szx=Hv[6],Szy=Hv[7],Szz=Hv[8];
    float Kq[4][4];
    Kq[0][0]=Sxx+Syy+Szz; Kq[0][1]=Syz-Szy;     Kq[0][2]=Szx-Sxz;     Kq[0][3]=Sxy-Syx;
    Kq[1][0]=Kq[0][1];    Kq[1][1]=Sxx-Syy-Szz; Kq[1][2]=Sxy+Syx;     Kq[1][3]=Szx+Sxz;
    Kq[2][0]=Kq[0][2];    Kq[2][1]=Kq[1][2];    Kq[2][2]=Syy-Sxx-Szz; Kq[2][3]=Syz+Szy;
    Kq[3][0]=Kq[0][3];    Kq[3][1]=Kq[1][3];    Kq[3][2]=Kq[2][3];    Kq[3][3]=Szz-Sxx-Syy;
    float fn=0.f;
    #pragma unroll
    for (int i=0;i<4;++i)
      #pragma unroll
      for (int j=0;j<4;++j) fn += Kq[i][j]*Kq[i][j];
    float sig=sqrtf(fn)+1e-30f;
    #pragma unroll
    for (int i=0;i<4;++i) Kq[i][i]+=sig;
    fn=0.f;
    #pragma unroll
    for (int i=0;i<4;++i)
      #pragma unroll
      for (int j=0;j<4;++j) fn += Kq[i][j]*Kq[i][j];
    float nsc=rsqrtf(fn+1e-38f);
    #pragma unroll
    for (int i=0;i<4;++i)
      #pragma unroll
      for (int j=0;j<4;++j) Kq[i][j]*=nsc;
    #pragma unroll
    for (int sqi=0;sqi<4;++sqi){
      float Bq[4][4]; float f2=0.f;
      #pragma unroll
      for (int i=0;i<4;++i)
        #pragma unroll
        for (int j=0;j<4;++j){
          float v=0.f;
          #pragma unroll
          for (int k=0;k<4;++k) v=fmaf(Kq[i][k],Kq[k][j],v);
          Bq[i][j]=v; f2+=v*v;
        }
      float isc=rsqrtf(f2+1e-38f);
      #pragma unroll
      for (int i=0;i<4;++i)
        #pragma unroll
        for (int j=0;j<4;++j) Kq[i][j]=Bq[i][j]*isc;
    }
    float q0=1.f,q1=0.31f,q2=0.67f,q3=0.93f;
    #pragma unroll
    for (int it=0;it<16;++it){
      float n0=Kq[0][0]*q0+Kq[0][1]*q1+Kq[0][2]*q2+Kq[0][3]*q3;
      float n1=Kq[1][0]*q0+Kq[1][1]*q1+Kq[1][2]*q2+Kq[1][3]*q3;
      float n2=Kq[2][0]*q0+Kq[2][1]*q1+Kq[2][2]*q2+Kq[2][3]*q3;
      float n3=Kq[3][0]*q0+Kq[3][1]*q1+Kq[3][2]*q2+Kq[3][3]*q3;
      float nn=rsqrtf(n0*n0+n1*n1+n2*n2+n3*n3+1e-38f);
      q0=n0*nn; q1=n1*nn; q2=n2*nn; q3=n3*nn;
    }
    float R00=q0*q0+q1*q1-q2*q2-q3*q3, R01=2.f*(q1*q2-q0*q3),       R02=2.f*(q1*q3+q0*q2);
    float R10=2.f*(q1*q2+q0*q3),       R11=q0*q0-q1*q1+q2*q2-q3*q3, R12=2.f*(q2*q3-q0*q1);
    float R20=2.f*(q1*q3-q0*q2),       R21=2.f*(q2*q3+q0*q1),       R22=q0*q0-q1*q1-q2*q2+q3*q3;
    float tx=c2x-(R00*c1x+R01*c1y+R02*c1z);
    float ty=c2y-(R10*c1x+R11*c1y+R12*c1z);
    float tz=c2z-(R20*c1x+R21*c1y+R22*c1z);
    float tn=sqrtf(tx*tx+ty*ty+tz*tz);
    float itn=1.f/fmaxf(tn,1e-12f);
    tx*=itn; ty*=itn; tz*=itn;
    if (cntTot < 4.5f){
      R00=1.f;R01=0.f;R02=0.f; R10=0.f;R11=1.f;R12=0.f; R20=0.f;R21=0.f;R22=1.f;
      tx=0.f; ty=0.f; tz=1.f;
    }
    float* Ro=out+b*9;
    Ro[0]=R00;Ro[1]=R01;Ro[2]=R02;Ro[3]=R10;Ro[4]=R11;Ro[5]=R12;Ro[6]=R20;Ro[7]=R21;Ro[8]=R22;
    float* to=out+BB*9+b*3;
    to[0]=tx; to[1]=ty; to[2]=tz;
  }
}

extern "C" void kernel_launch(void* const* d_in, const int* in_sizes, int n_in,
                              void* d_out, int out_size, void* d_ws, size_t ws_size,
                              hipStream_t stream){
  const float* pos1=(const float*)d_in[0];
  const float* pos2=(const float*)d_in[1];
  const float* sc  =(const float*)d_in[2];
  // d_in[3] = K (unused by the reference)
  const float* w1  =(const float*)d_in[4];
  const float* b1  =(const float*)d_in[5];
  const float* w2  =(const float*)d_in[6];
  const float* b2  =(const float*)d_in[7];
  float* ws=(float*)d_ws;
  float* out=(float*)d_out;

  k_prep <<<dim3(257), dim3(256), 0, stream>>>(sc, w1, b1, w2, b2, ws);
  k_stats<<<dim3(512), dim3(256), 0, stream>>>(sc, pos1, ws);
  k_final<<<dim3(BB),  dim3(256), 0, stream>>>(pos2, ws, out);
}